// Round 8
// baseline (42917.206 us; speedup 1.0000x reference)
//
#include <hip/hip_runtime.h>
#include <math.h>

#define BSZ 1024
#define NNODE 200
#define DH 512
#define DK 512
#define NSTEP 200

// ---------------- threefry2x32 (JAX-exact, partitionable mode) ----------------
__device__ __forceinline__ unsigned rotl32(unsigned x, int r) {
  return (x << r) | (x >> (32 - r));
}

__device__ __forceinline__ void tf2x32(unsigned k0, unsigned k1,
                                       unsigned c0, unsigned c1,
                                       unsigned& o0, unsigned& o1) {
  unsigned ks2 = k0 ^ k1 ^ 0x1BD11BDAu;
  unsigned x0 = c0 + k0, x1 = c1 + k1;
#define TF_RND(r) { x0 += x1; x1 = rotl32(x1, (r)); x1 ^= x0; }
  TF_RND(13) TF_RND(15) TF_RND(26) TF_RND(6)
  x0 += k1;  x1 += ks2 + 1u;
  TF_RND(17) TF_RND(29) TF_RND(16) TF_RND(24)
  x0 += ks2; x1 += k0 + 2u;
  TF_RND(13) TF_RND(15) TF_RND(26) TF_RND(6)
  x0 += k0;  x1 += k1 + 3u;
  TF_RND(17) TF_RND(29) TF_RND(16) TF_RND(24)
  x0 += k1;  x1 += ks2 + 4u;
  TF_RND(13) TF_RND(15) TF_RND(26) TF_RND(6)
  x0 += ks2; x1 += k0 + 5u;
#undef TF_RND
  o0 = x0; o1 = x1;
}

__device__ __forceinline__ void step_key(int i, unsigned& k0, unsigned& k1) {
  tf2x32(0u, 42u, 0u, (unsigned)i, k0, k1);
}
__device__ __forceinline__ unsigned elem_bits(unsigned k0, unsigned k1, unsigned m) {
  unsigned o0, o1;
  tf2x32(k0, k1, 0u, m, o0, o1);
  return o0 ^ o1;
}

// -------- XLA f32 tanh (EmitFastTanh, with_fma=true -> fmuladd Horner) -------
__device__ __forceinline__ float xla_tanh_f32(float x) {
  const float kMax = 7.90531110763549805f;
  float xc = fminf(fmaxf(x, -kMax), kMax);
  float x2 = xc * xc;
  float p = -2.76076847742355e-16f;
  p = __builtin_fmaf(x2, p, 2.00018790482477e-13f);
  p = __builtin_fmaf(x2, p, -8.60467152213735e-11f);
  p = __builtin_fmaf(x2, p, 5.12229709037114e-08f);
  p = __builtin_fmaf(x2, p, 1.48572235717979e-05f);
  p = __builtin_fmaf(x2, p, 6.37261928875436e-04f);
  p = __builtin_fmaf(x2, p, 4.89352455891786e-03f);
  float num = xc * p;
  float q = 1.19825839466702e-06f;
  q = __builtin_fmaf(x2, q, 1.18534705686654e-04f);
  q = __builtin_fmaf(x2, q, 2.26843463243900e-03f);
  q = __builtin_fmaf(x2, q, 4.89352518554385e-03f);
  float r = num / q;
  return (fabsf(x) < 0.0004f) ? x : r;
}

// ---------------- XLA f32 log (Cephes, plain fmul/fadd as in VF32Log) --------
__device__ __forceinline__ float xla_log_f32(float x) {
#pragma clang fp contract(off)
  unsigned bits = __float_as_uint(x);
  int e = (int)((bits >> 23) & 0xffu) - 126;          // x = m * 2^e, m in [0.5,1)
  float m = __uint_as_float((bits & 0x007fffffu) | 0x3f000000u);
  bool c = m < 0.707106781186547524f;                 // sqrt(0.5)
  e = c ? (e - 1) : e;
  m = c ? (m + m) : m;
  m = m - 1.0f;
  float z = m * m;
  float y = 7.0376836292e-2f;
  y = y * m + (-1.1514610310e-1f);
  y = y * m + 1.1676998740e-1f;
  y = y * m + (-1.2420140846e-1f);
  y = y * m + 1.4249322787e-1f;
  y = y * m + (-1.6668057665e-1f);
  y = y * m + 2.0000714765e-1f;
  y = y * m + (-2.4999993993e-1f);
  y = y * m + 3.3333331174e-1f;
  y = y * m;
  y = y * z;
  float ef = (float)e;
  float t1 = ef * (-2.12194440e-4f);
  y = y + t1;
  float t2 = z * 0.5f;
  y = y - t2;
  float r = m + y;
  float t3 = ef * 0.693359375f;
  r = r + t3;
  return r;
}

// ---------------- setup kernels (f32, gold-faithful orders) ----------------

// Hbar[b][d] = (sum over n ascending, plain f32 adds) / 200.0f
__global__ void k_hbar(const float* __restrict__ H, float* __restrict__ Hbar) {
#pragma clang fp contract(off)
  int idx = blockIdx.x * 256 + threadIdx.x;  // 1024*512
  int b = idx >> 9, d = idx & 511;
  const float* p = H + (size_t)b * NNODE * DH + d;
  float s = 0.0f;
  for (int n = 0; n < NNODE; n++) s = s + p[(size_t)n * DH];
  Hbar[idx] = s / 200.0f;
}

// KT[b][k][n] = FMA-chain over d ascending of H[b,n,d]*WK[d,k]  (values as before,
// TRANSPOSED layout so k_step reads are lane-coalesced without LDS staging)
__global__ __launch_bounds__(256) void k_K(const float* __restrict__ H,
                                           const float* __restrict__ WK,
                                           float* __restrict__ KT) {
  __shared__ float hr[8][DH];        // 16 KiB
  __shared__ float ts[DK * 9];       // retile pad-9: 18.4 KiB, conflict-free
  int g = blockIdx.x;                // 1024*25 blocks, 8 rows each
  int b = g / 25;
  int r0 = (g % 25) * 8;
  int t = threadIdx.x;
  const float* Hb = H + (size_t)b * NNODE * DH + (size_t)r0 * DH;
  for (int e = t; e < 8 * DH; e += 256) hr[e >> 9][e & 511] = Hb[e];
  __syncthreads();
  int k0 = t, k1 = t + 256;
  float a[8][2];
#pragma unroll
  for (int r = 0; r < 8; r++) { a[r][0] = 0.0f; a[r][1] = 0.0f; }
  for (int d = 0; d < DH; d++) {
    float w0 = WK[(size_t)d * DK + k0], w1 = WK[(size_t)d * DK + k1];
#pragma unroll
    for (int r = 0; r < 8; r++) {
      a[r][0] = __builtin_fmaf(hr[r][d], w0, a[r][0]);
      a[r][1] = __builtin_fmaf(hr[r][d], w1, a[r][1]);
    }
  }
#pragma unroll
  for (int r = 0; r < 8; r++) {
    ts[k0 * 9 + r] = a[r][0];
    ts[k1 * 9 + r] = a[r][1];
  }
  __syncthreads();
  float* Ko = KT + (size_t)b * DK * NNODE + r0;
  for (int i = t; i < DK * 8; i += 256) {
    int k = i >> 3, r = i & 7;
    Ko[(size_t)k * NNODE + r] = ts[k * 9 + r];
  }
}

// acc[b][j] = FMA-chain k=0..511 of Hbar[b,k]*WQ[k,j] (prefix of the 1536-chain)
__global__ __launch_bounds__(256) void k_acc512(const float* __restrict__ Hbar,
                                                const float* __restrict__ WQ,
                                                float* __restrict__ acc) {
  __shared__ float hb[DH];
  int b = blockIdx.x, t = threadIdx.x;
  for (int e = t; e < DH; e += 256) hb[e] = Hbar[(size_t)b * DH + e];
  __syncthreads();
  int j0 = t, j1 = t + 256;
  float a0 = 0.0f, a1 = 0.0f;
  for (int k = 0; k < DH; k++) {
    float w0 = WQ[(size_t)k * DK + j0], w1 = WQ[(size_t)k * DK + j1];
    a0 = __builtin_fmaf(hb[k], w0, a0);
    a1 = __builtin_fmaf(hb[k], w1, a1);
  }
  acc[(size_t)b * DK + j0] = a0;
  acc[(size_t)b * DK + j1] = a1;
}

// Q0 = continue chain with v1 part (k=512..1023) then vf part (k=1024..1535)
__global__ __launch_bounds__(256) void k_q0(const float* __restrict__ acc,
                                            const float* __restrict__ WQ,
                                            const float* __restrict__ v1,
                                            const float* __restrict__ vf,
                                            float* __restrict__ Q) {
  __shared__ float s1[DH], s2[DH];
  int b = blockIdx.x, t = threadIdx.x;
  for (int e = t; e < DH; e += 256) { s1[e] = v1[e]; s2[e] = vf[e]; }
  __syncthreads();
  int j0 = t, j1 = t + 256;
  float a0 = acc[(size_t)b * DK + j0], a1 = acc[(size_t)b * DK + j1];
  for (int k = 0; k < DH; k++) {
    float w0 = WQ[(size_t)(512 + k) * DK + j0], w1 = WQ[(size_t)(512 + k) * DK + j1];
    a0 = __builtin_fmaf(s1[k], w0, a0);
    a1 = __builtin_fmaf(s1[k], w1, a1);
  }
  for (int k = 0; k < DH; k++) {
    float w0 = WQ[(size_t)(1024 + k) * DK + j0], w1 = WQ[(size_t)(1024 + k) * DK + j1];
    a0 = __builtin_fmaf(s2[k], w0, a0);
    a1 = __builtin_fmaf(s2[k], w1, a1);
  }
  Q[(size_t)b * DK + j0] = a0;
  Q[(size_t)b * DK + j1] = a1;
}

// Q (steps>=1) = acc chain continued with Hpi part then Hpi0 part. 8 b per block.
__global__ __launch_bounds__(256) void k_q(const float* __restrict__ acc,
                                           const float* __restrict__ WQ,
                                           const float* __restrict__ Hpi,
                                           const float* __restrict__ Hpi0,
                                           float* __restrict__ Q) {
  __shared__ float hp[8][DH], hp0[8][DH];  // 32 KiB
  int b0 = blockIdx.x * 8, t = threadIdx.x;
  for (int e = t; e < 8 * DH; e += 256) {
    hp[e >> 9][e & 511]  = Hpi[(size_t)b0 * DH + e];
    hp0[e >> 9][e & 511] = Hpi0[(size_t)b0 * DH + e];
  }
  __syncthreads();
  int j0 = t, j1 = t + 256;
  float a[8][2];
#pragma unroll
  for (int r = 0; r < 8; r++) {
    a[r][0] = acc[(size_t)(b0 + r) * DK + j0];
    a[r][1] = acc[(size_t)(b0 + r) * DK + j1];
  }
  for (int k = 0; k < DH; k++) {
    float w0 = WQ[(size_t)(512 + k) * DK + j0], w1 = WQ[(size_t)(512 + k) * DK + j1];
#pragma unroll
    for (int r = 0; r < 8; r++) {
      a[r][0] = __builtin_fmaf(hp[r][k], w0, a[r][0]);
      a[r][1] = __builtin_fmaf(hp[r][k], w1, a[r][1]);
    }
  }
  for (int k = 0; k < DH; k++) {
    float w0 = WQ[(size_t)(1024 + k) * DK + j0], w1 = WQ[(size_t)(1024 + k) * DK + j1];
#pragma unroll
    for (int r = 0; r < 8; r++) {
      a[r][0] = __builtin_fmaf(hp0[r][k], w0, a[r][0]);
      a[r][1] = __builtin_fmaf(hp0[r][k], w1, a[r][1]);
    }
  }
#pragma unroll
  for (int r = 0; r < 8; r++) {
    Q[(size_t)(b0 + r) * DK + j0] = a[r][0];
    Q[(size_t)(b0 + r) * DK + j1] = a[r][1];
  }
}

__global__ void k_copy(const float* __restrict__ src, float* __restrict__ dst) {
  int i = blockIdx.x * 256 + threadIdx.x;
  dst[i] = src[i];
}

// ---------------- per-step: U, logits, gumbel, argmax, gather ----------------
// U: W=16 strided accumulators (k mod 16), separate mul/add, shuffle-halving
// tree — BIT-IDENTICAL to the R7-passing order. KT layout gives lane-coalesced
// direct global reads (no LDS staging, no barriers in the k-loop).
// Serpentine b-mapping across steps: L3 (256 MB) retains the tail of K (419 MB).
__global__ __launch_bounds__(256) void k_step(const float* __restrict__ KT,
                                              const float* __restrict__ Q,
                                              const float* __restrict__ H,
                                              float* __restrict__ Hpi,
                                              int* __restrict__ out, int step) {
  __shared__ float Ql[DK];
  __shared__ float zl[NNODE];
  __shared__ int   pil;
  int blk = blockIdx.x;
  int b = (step & 1) ? (BSZ - 1 - blk) : blk;   // serpentine sweep over b
  int t = threadIdx.x;
  for (int e = t; e < DK; e += 256) Ql[e] = Q[(size_t)b * DK + e];
  __syncthreads();
  const float* Kb = KT + (size_t)b * DK * NNODE;
  float l[16];
#pragma unroll
  for (int j = 0; j < 16; j++) l[j] = 0.0f;
  if (t < NNODE) {
#pragma clang fp contract(off)
    for (int c = 0; c < DK / 16; c++) {     // 32 chunks, k ascending
      float kb[16];
#pragma unroll
      for (int u = 0; u < 16; u++)
        kb[u] = Kb[(size_t)(c * 16 + u) * NNODE + t];
#pragma unroll
      for (int u = 0; u < 16; u++) {
        float prod = kb[u] * Ql[c * 16 + u];  // separate mul rounding
        l[u] = l[u] + prod;                   // lane-strided fadd accumulate
      }
    }
  }
  if (t < NNODE) {
#pragma clang fp contract(off)
    // shuffle-halving horizontal reduce over 16 lanes:
#pragma unroll
    for (int j = 0; j < 8; j++) l[j] = l[j] + l[j + 8];
#pragma unroll
    for (int j = 0; j < 4; j++) l[j] = l[j] + l[j + 4];
#pragma unroll
    for (int j = 0; j < 2; j++) l[j] = l[j] + l[j + 2];
    float U = l[0] + l[1];
    const float inv = 1.0f / sqrtf(512.0f);
    float u = U * inv;
    float logit = 10.0f * xla_tanh_f32(u);
    unsigned k0, k1;
    step_key(step, k0, k1);
    unsigned bits = elem_bits(k0, k1, (unsigned)(b * NNODE + t));
    unsigned fb = (bits >> 9) | 0x3F800000u;
    float uf = __uint_as_float(fb) - 1.0f;    // [0,1), exact
    const float tinyf = 1.17549435e-38f;
    float v = uf * 1.0f;
    v = v + tinyf;
    v = fmaxf(tinyf, v);
    float L1 = xla_log_f32(v);
    float g = -xla_log_f32(-L1);
    zl[t] = g + logit;
  }
  __syncthreads();
  if (t < 64) {  // wave 0: argmax, first-occurrence tie rule, f32 compares
    float bv = -__builtin_inff();
    int bi = 0;
    for (int n = t; n < NNODE; n += 64) {
      float zv = zl[n];
      if (zv > bv) { bv = zv; bi = n; }
    }
    for (int off = 32; off; off >>= 1) {
      float ov = __shfl_down(bv, off);
      int   oi = __shfl_down(bi, off);
      if (ov > bv || (ov == bv && oi < bi)) { bv = ov; bi = oi; }
    }
    if (t == 0) pil = bi;
  }
  __syncthreads();
  int pi = pil;
  if (t == 0) {
    out[b * (NSTEP + 1) + step + 1] = pi;
    if (step == 0) out[b * (NSTEP + 1)] = pi;  // Pi duplicates step-0 pick at col 0
  }
  const float* src = H + (size_t)b * NNODE * DH + (size_t)pi * DH;
  for (int e = t; e < DH; e += 256) Hpi[(size_t)b * DH + e] = src[e];  // exact copy
}

extern "C" void kernel_launch(void* const* d_in, const int* in_sizes, int n_in,
                              void* d_out, int out_size, void* d_ws, size_t ws_size,
                              hipStream_t stream) {
  (void)in_sizes; (void)n_in; (void)out_size; (void)ws_size;
  const float* H  = (const float*)d_in[1];
  const float* WQ = (const float*)d_in[2];
  const float* WK = (const float*)d_in[3];
  const float* v1 = (const float*)d_in[4];
  const float* vf = (const float*)d_in[5];
  int* out = (int*)d_out;

  float* ws = (float*)d_ws;
  const size_t KSZ = (size_t)BSZ * NNODE * DK;  // 419.4 MB
  const size_t S = (size_t)BSZ * 512;
  float* KT   = ws;
  float* Hbar = ws + KSZ;
  float* acc  = ws + KSZ + 1 * S;
  float* Q    = ws + KSZ + 2 * S;
  float* Hpi  = ws + KSZ + 3 * S;
  float* Hpi0 = ws + KSZ + 4 * S;

  // setup (all bit-faithful f32)
  k_hbar  <<<2048, 256, 0, stream>>>(H, Hbar);
  k_K     <<<BSZ * 25, 256, 0, stream>>>(H, WK, KT);
  k_acc512<<<BSZ, 256, 0, stream>>>(Hbar, WQ, acc);
  k_q0    <<<BSZ, 256, 0, stream>>>(acc, WQ, v1, vf, Q);

  // step 0
  k_step  <<<BSZ, 256, 0, stream>>>(KT, Q, H, Hpi, out, 0);
  k_copy  <<<2048, 256, 0, stream>>>(Hpi, Hpi0);  // freeze H_pi_1 = pick0

  // steps 1..199
  for (int i = 1; i < NSTEP; i++) {
    k_q   <<<BSZ / 8, 256, 0, stream>>>(acc, WQ, Hpi, Hpi0, Q);
    k_step<<<BSZ, 256, 0, stream>>>(KT, Q, H, Hpi, out, i);
  }
}

// Round 9
// 27959.012 us; speedup vs baseline: 1.5350x; 1.5350x over previous
//
#include <hip/hip_runtime.h>
#include <math.h>

#define BSZ 1024
#define NNODE 200
#define DH 512
#define DK 512
#define NSTEP 200
#define G 4      // batch rows per block
#define TPB 512

// ---------------- threefry2x32 (JAX-exact, partitionable mode) ----------------
__device__ __forceinline__ unsigned rotl32(unsigned x, int r) {
  return (x << r) | (x >> (32 - r));
}

__device__ __forceinline__ void tf2x32(unsigned k0, unsigned k1,
                                       unsigned c0, unsigned c1,
                                       unsigned& o0, unsigned& o1) {
  unsigned ks2 = k0 ^ k1 ^ 0x1BD11BDAu;
  unsigned x0 = c0 + k0, x1 = c1 + k1;
#define TF_RND(r) { x0 += x1; x1 = rotl32(x1, (r)); x1 ^= x0; }
  TF_RND(13) TF_RND(15) TF_RND(26) TF_RND(6)
  x0 += k1;  x1 += ks2 + 1u;
  TF_RND(17) TF_RND(29) TF_RND(16) TF_RND(24)
  x0 += ks2; x1 += k0 + 2u;
  TF_RND(13) TF_RND(15) TF_RND(26) TF_RND(6)
  x0 += k0;  x1 += k1 + 3u;
  TF_RND(17) TF_RND(29) TF_RND(16) TF_RND(24)
  x0 += k1;  x1 += ks2 + 4u;
  TF_RND(13) TF_RND(15) TF_RND(26) TF_RND(6)
  x0 += ks2; x1 += k0 + 5u;
#undef TF_RND
  o0 = x0; o1 = x1;
}

__device__ __forceinline__ void step_key(int i, unsigned& k0, unsigned& k1) {
  tf2x32(0u, 42u, 0u, (unsigned)i, k0, k1);
}
__device__ __forceinline__ unsigned elem_bits(unsigned k0, unsigned k1, unsigned m) {
  unsigned o0, o1;
  tf2x32(k0, k1, 0u, m, o0, o1);
  return o0 ^ o1;
}

// -------- XLA f32 tanh (EmitFastTanh, with_fma=true -> fmuladd Horner) -------
__device__ __forceinline__ float xla_tanh_f32(float x) {
  const float kMax = 7.90531110763549805f;
  float xc = fminf(fmaxf(x, -kMax), kMax);
  float x2 = xc * xc;
  float p = -2.76076847742355e-16f;
  p = __builtin_fmaf(x2, p, 2.00018790482477e-13f);
  p = __builtin_fmaf(x2, p, -8.60467152213735e-11f);
  p = __builtin_fmaf(x2, p, 5.12229709037114e-08f);
  p = __builtin_fmaf(x2, p, 1.48572235717979e-05f);
  p = __builtin_fmaf(x2, p, 6.37261928875436e-04f);
  p = __builtin_fmaf(x2, p, 4.89352455891786e-03f);
  float num = xc * p;
  float q = 1.19825839466702e-06f;
  q = __builtin_fmaf(x2, q, 1.18534705686654e-04f);
  q = __builtin_fmaf(x2, q, 2.26843463243900e-03f);
  q = __builtin_fmaf(x2, q, 4.89352518554385e-03f);
  float r = num / q;
  return (fabsf(x) < 0.0004f) ? x : r;
}

// ---------------- XLA f32 log (Cephes, plain fmul/fadd as in VF32Log) --------
__device__ __forceinline__ float xla_log_f32(float x) {
#pragma clang fp contract(off)
  unsigned bits = __float_as_uint(x);
  int e = (int)((bits >> 23) & 0xffu) - 126;          // x = m * 2^e, m in [0.5,1)
  float m = __uint_as_float((bits & 0x007fffffu) | 0x3f000000u);
  bool c = m < 0.707106781186547524f;                 // sqrt(0.5)
  e = c ? (e - 1) : e;
  m = c ? (m + m) : m;
  m = m - 1.0f;
  float z = m * m;
  float y = 7.0376836292e-2f;
  y = y * m + (-1.1514610310e-1f);
  y = y * m + 1.1676998740e-1f;
  y = y * m + (-1.2420140846e-1f);
  y = y * m + 1.4249322787e-1f;
  y = y * m + (-1.6668057665e-1f);
  y = y * m + 2.0000714765e-1f;
  y = y * m + (-2.4999993993e-1f);
  y = y * m + 3.3333331174e-1f;
  y = y * m;
  y = y * z;
  float ef = (float)e;
  float t1 = ef * (-2.12194440e-4f);
  y = y + t1;
  float t2 = z * 0.5f;
  y = y - t2;
  float r = m + y;
  float t3 = ef * 0.693359375f;
  r = r + t3;
  return r;
}

// ---------------- setup kernels (f32, gold-faithful orders) ----------------

// Hbar[b][d] = (sum over n ascending, plain f32 adds) / 200.0f
__global__ void k_hbar(const float* __restrict__ H, float* __restrict__ Hbar) {
#pragma clang fp contract(off)
  int idx = blockIdx.x * 256 + threadIdx.x;  // 1024*512
  int b = idx >> 9, d = idx & 511;
  const float* p = H + (size_t)b * NNODE * DH + d;
  float s = 0.0f;
  for (int n = 0; n < NNODE; n++) s = s + p[(size_t)n * DH];
  Hbar[idx] = s / 200.0f;
}

// KT[b][k][n] = FMA-chain over d ascending of H[b,n,d]*WK[d,k]  (transposed layout)
__global__ __launch_bounds__(256) void k_K(const float* __restrict__ H,
                                           const float* __restrict__ WK,
                                           float* __restrict__ KT) {
  __shared__ float hr[8][DH];        // 16 KiB
  __shared__ float ts[DK * 9];       // retile pad-9, conflict-free
  int g = blockIdx.x;                // 1024*25 blocks, 8 rows each
  int b = g / 25;
  int r0 = (g % 25) * 8;
  int t = threadIdx.x;
  const float* Hb = H + (size_t)b * NNODE * DH + (size_t)r0 * DH;
  for (int e = t; e < 8 * DH; e += 256) hr[e >> 9][e & 511] = Hb[e];
  __syncthreads();
  int k0 = t, k1 = t + 256;
  float a[8][2];
#pragma unroll
  for (int r = 0; r < 8; r++) { a[r][0] = 0.0f; a[r][1] = 0.0f; }
  for (int d = 0; d < DH; d++) {
    float w0 = WK[(size_t)d * DK + k0], w1 = WK[(size_t)d * DK + k1];
#pragma unroll
    for (int r = 0; r < 8; r++) {
      a[r][0] = __builtin_fmaf(hr[r][d], w0, a[r][0]);
      a[r][1] = __builtin_fmaf(hr[r][d], w1, a[r][1]);
    }
  }
#pragma unroll
  for (int r = 0; r < 8; r++) {
    ts[k0 * 9 + r] = a[r][0];
    ts[k1 * 9 + r] = a[r][1];
  }
  __syncthreads();
  float* Ko = KT + (size_t)b * DK * NNODE + r0;
  for (int i = t; i < DK * 8; i += 256) {
    int k = i >> 3, r = i & 7;
    Ko[(size_t)k * NNODE + r] = ts[k * 9 + r];
  }
}

// acc[b][j] = FMA-chain k=0..511 of Hbar[b,k]*WQ[k,j] (prefix of the 1536-chain)
__global__ __launch_bounds__(256) void k_acc512(const float* __restrict__ Hbar,
                                                const float* __restrict__ WQ,
                                                float* __restrict__ acc) {
  __shared__ float hb[DH];
  int b = blockIdx.x, t = threadIdx.x;
  for (int e = t; e < DH; e += 256) hb[e] = Hbar[(size_t)b * DH + e];
  __syncthreads();
  int j0 = t, j1 = t + 256;
  float a0 = 0.0f, a1 = 0.0f;
  for (int k = 0; k < DH; k++) {
    float w0 = WQ[(size_t)k * DK + j0], w1 = WQ[(size_t)k * DK + j1];
    a0 = __builtin_fmaf(hb[k], w0, a0);
    a1 = __builtin_fmaf(hb[k], w1, a1);
  }
  acc[(size_t)b * DK + j0] = a0;
  acc[(size_t)b * DK + j1] = a1;
}

// ---------------- the fused 200-step decoder: one block owns G batch rows ----
__global__ __launch_bounds__(TPB) void k_mega(const float* __restrict__ KT,
                                              const float* __restrict__ acc,
                                              const float* __restrict__ WQ,
                                              const float* __restrict__ H,
                                              const float* __restrict__ v1,
                                              const float* __restrict__ vf,
                                              int* __restrict__ out) {
  __shared__ float hpI[DH][G];     // interleaved [k][bb] : current pick
  __shared__ float hp0I[DH][G];    // first pick (frozen after step 0)
  __shared__ float Qs[G][DK];
  __shared__ float accs[G][DK];
  __shared__ float zl[G][NNODE];
  __shared__ int   pil[G];
  int t = threadIdx.x;
  int b0 = blockIdx.x * G;

  // stage acc rows + v1/vf as the step-0 "picks" (h_c0 = [Hbar, v1, vf])
  for (int e = t; e < G * DK; e += TPB) {
    int bb = e >> 9, j = e & 511;
    accs[bb][j] = acc[(size_t)(b0 + bb) * DK + j];
  }
  for (int e = t; e < DH; e += TPB) {
    float a = v1[e], bv = vf[e];
#pragma unroll
    for (int bb = 0; bb < G; bb++) { hpI[e][bb] = a; hp0I[e][bb] = bv; }
  }
  __syncthreads();

  for (int step = 0; step < NSTEP; step++) {
    // ---- Q phase: thread owns column j=t; 4 chains (one per bb).
    // Chain per (bb,j): a=accs; k=0..511 hp part (W rows 512..1023);
    // then hp0 part (rows 1024..1535). FMA, k ascending — R7/R8-exact.
    {
      float a0 = accs[0][t], a1 = accs[1][t], a2 = accs[2][t], a3 = accs[3][t];
      const float* Wp = WQ + (size_t)512 * DK + t;
      for (int k = 0; k < DH; k += 4) {
        float w0 = Wp[(size_t)(k + 0) * DK];
        float w1 = Wp[(size_t)(k + 1) * DK];
        float w2 = Wp[(size_t)(k + 2) * DK];
        float w3 = Wp[(size_t)(k + 3) * DK];
        float4 h0 = *(const float4*)&hpI[k + 0][0];
        float4 h1 = *(const float4*)&hpI[k + 1][0];
        float4 h2 = *(const float4*)&hpI[k + 2][0];
        float4 h3 = *(const float4*)&hpI[k + 3][0];
        a0 = __builtin_fmaf(h0.x, w0, a0); a1 = __builtin_fmaf(h0.y, w0, a1);
        a2 = __builtin_fmaf(h0.z, w0, a2); a3 = __builtin_fmaf(h0.w, w0, a3);
        a0 = __builtin_fmaf(h1.x, w1, a0); a1 = __builtin_fmaf(h1.y, w1, a1);
        a2 = __builtin_fmaf(h1.z, w1, a2); a3 = __builtin_fmaf(h1.w, w1, a3);
        a0 = __builtin_fmaf(h2.x, w2, a0); a1 = __builtin_fmaf(h2.y, w2, a1);
        a2 = __builtin_fmaf(h2.z, w2, a2); a3 = __builtin_fmaf(h2.w, w2, a3);
        a0 = __builtin_fmaf(h3.x, w3, a0); a1 = __builtin_fmaf(h3.y, w3, a1);
        a2 = __builtin_fmaf(h3.z, w3, a2); a3 = __builtin_fmaf(h3.w, w3, a3);
      }
      const float* Wp2 = WQ + (size_t)1024 * DK + t;
      for (int k = 0; k < DH; k += 4) {
        float w0 = Wp2[(size_t)(k + 0) * DK];
        float w1 = Wp2[(size_t)(k + 1) * DK];
        float w2 = Wp2[(size_t)(k + 2) * DK];
        float w3 = Wp2[(size_t)(k + 3) * DK];
        float4 h0 = *(const float4*)&hp0I[k + 0][0];
        float4 h1 = *(const float4*)&hp0I[k + 1][0];
        float4 h2 = *(const float4*)&hp0I[k + 2][0];
        float4 h3 = *(const float4*)&hp0I[k + 3][0];
        a0 = __builtin_fmaf(h0.x, w0, a0); a1 = __builtin_fmaf(h0.y, w0, a1);
        a2 = __builtin_fmaf(h0.z, w0, a2); a3 = __builtin_fmaf(h0.w, w0, a3);
        a0 = __builtin_fmaf(h1.x, w1, a0); a1 = __builtin_fmaf(h1.y, w1, a1);
        a2 = __builtin_fmaf(h1.z, w1, a2); a3 = __builtin_fmaf(h1.w, w1, a3);
        a0 = __builtin_fmaf(h2.x, w2, a0); a1 = __builtin_fmaf(h2.y, w2, a1);
        a2 = __builtin_fmaf(h2.z, w2, a2); a3 = __builtin_fmaf(h2.w, w2, a3);
        a0 = __builtin_fmaf(h3.x, w3, a0); a1 = __builtin_fmaf(h3.y, w3, a1);
        a2 = __builtin_fmaf(h3.z, w3, a2); a3 = __builtin_fmaf(h3.w, w3, a3);
      }
      Qs[0][t] = a0; Qs[1][t] = a1; Qs[2][t] = a2; Qs[3][t] = a3;
    }
    __syncthreads();

    // ---- U/z/argmax/gather: two passes, each handling 2 bb (block halves)
    for (int pass = 0; pass < 2; pass++) {
      int bb = pass * 2 + (t >= 256 ? 1 : 0);
      int tl = t & 255;             // lane within half
      int b = b0 + bb;
      if (tl < NNODE) {
#pragma clang fp contract(off)
        const float* Kb = KT + (size_t)b * DK * NNODE;
        float l[16];
#pragma unroll
        for (int j = 0; j < 16; j++) l[j] = 0.0f;
        for (int c = 0; c < DK / 16; c++) {   // 32 chunks, k ascending
          float kb[16];
#pragma unroll
          for (int u = 0; u < 16; u++)
            kb[u] = Kb[(size_t)(c * 16 + u) * NNODE + tl];
          float4 q0 = *(const float4*)&Qs[bb][c * 16 + 0];
          float4 q1 = *(const float4*)&Qs[bb][c * 16 + 4];
          float4 q2 = *(const float4*)&Qs[bb][c * 16 + 8];
          float4 q3 = *(const float4*)&Qs[bb][c * 16 + 12];
          float qv[16] = {q0.x,q0.y,q0.z,q0.w, q1.x,q1.y,q1.z,q1.w,
                          q2.x,q2.y,q2.z,q2.w, q3.x,q3.y,q3.z,q3.w};
#pragma unroll
          for (int u = 0; u < 16; u++) {
            float prod = kb[u] * qv[u];     // separate mul rounding
            l[u] = l[u] + prod;             // lane-strided fadd accumulate
          }
        }
        // shuffle-halving horizontal reduce over 16 lanes:
#pragma unroll
        for (int j = 0; j < 8; j++) l[j] = l[j] + l[j + 8];
#pragma unroll
        for (int j = 0; j < 4; j++) l[j] = l[j] + l[j + 4];
#pragma unroll
        for (int j = 0; j < 2; j++) l[j] = l[j] + l[j + 2];
        float U = l[0] + l[1];
        const float inv = 1.0f / sqrtf(512.0f);
        float u = U * inv;
        float logit = 10.0f * xla_tanh_f32(u);
        unsigned kk0, kk1;
        step_key(step, kk0, kk1);
        unsigned bits = elem_bits(kk0, kk1, (unsigned)(b * NNODE + tl));
        unsigned fb = (bits >> 9) | 0x3F800000u;
        float uf = __uint_as_float(fb) - 1.0f;    // [0,1), exact
        const float tinyf = 1.17549435e-38f;
        float v = uf * 1.0f;
        v = v + tinyf;
        v = fmaxf(tinyf, v);
        float L1 = xla_log_f32(v);
        float gmb = -xla_log_f32(-L1);
        zl[bb][tl] = gmb + logit;
      }
      __syncthreads();
      if (tl < 64) {  // wave0 of each half: argmax, first-occurrence tie rule
        float bv = -__builtin_inff();
        int bi = 0;
        for (int n = tl; n < NNODE; n += 64) {
          float zv = zl[bb][n];
          if (zv > bv) { bv = zv; bi = n; }
        }
        for (int off = 32; off; off >>= 1) {
          float ov = __shfl_down(bv, off);
          int   oi = __shfl_down(bi, off);
          if (ov > bv || (ov == bv && oi < bi)) { bv = ov; bi = oi; }
        }
        if (tl == 0) {
          pil[bb] = bi;
          out[b * (NSTEP + 1) + step + 1] = bi;
          if (step == 0) out[b * (NSTEP + 1)] = bi;  // duplicated step-0 pick
        }
      }
      __syncthreads();
      {   // gather H[b, pi] into hpI (exact copy)
        int pi = pil[bb];
        const float* src = H + ((size_t)b * NNODE + pi) * DH;
        for (int e = tl; e < DH; e += 256) hpI[e][bb] = src[e];
      }
      __syncthreads();
    }
    if (step == 0) {  // freeze H_pi_1 = step-0 pick
      for (int e = t; e < DH * G; e += TPB) hp0I[e >> 2][e & 3] = hpI[e >> 2][e & 3];
      __syncthreads();
    }
  }
}

extern "C" void kernel_launch(void* const* d_in, const int* in_sizes, int n_in,
                              void* d_out, int out_size, void* d_ws, size_t ws_size,
                              hipStream_t stream) {
  (void)in_sizes; (void)n_in; (void)out_size; (void)ws_size;
  const float* H  = (const float*)d_in[1];
  const float* WQ = (const float*)d_in[2];
  const float* WK = (const float*)d_in[3];
  const float* v1 = (const float*)d_in[4];
  const float* vf = (const float*)d_in[5];
  int* out = (int*)d_out;

  float* ws = (float*)d_ws;
  const size_t KSZ = (size_t)BSZ * NNODE * DK;  // 419.4 MB
  const size_t S = (size_t)BSZ * 512;
  float* KT   = ws;
  float* Hbar = ws + KSZ;
  float* acc  = ws + KSZ + S;

  k_hbar  <<<2048, 256, 0, stream>>>(H, Hbar);
  k_K     <<<BSZ * 25, 256, 0, stream>>>(H, WK, KT);
  k_acc512<<<BSZ, 256, 0, stream>>>(Hbar, WQ, acc);
  k_mega  <<<BSZ / G, TPB, 0, stream>>>(KT, acc, WQ, H, v1, vf, out);
}

// Round 10
// 27817.914 us; speedup vs baseline: 1.5428x; 1.0051x over previous
//
#include <hip/hip_runtime.h>
#include <math.h>

#define BSZ 1024
#define NNODE 200
#define DH 512
#define DK 512
#define NSTEP 200
#define G 4       // batch rows per block
#define TPB 1024

// ---------------- threefry2x32 (JAX-exact, partitionable mode) ----------------
__device__ __forceinline__ unsigned rotl32(unsigned x, int r) {
  return (x << r) | (x >> (32 - r));
}

__device__ __forceinline__ void tf2x32(unsigned k0, unsigned k1,
                                       unsigned c0, unsigned c1,
                                       unsigned& o0, unsigned& o1) {
  unsigned ks2 = k0 ^ k1 ^ 0x1BD11BDAu;
  unsigned x0 = c0 + k0, x1 = c1 + k1;
#define TF_RND(r) { x0 += x1; x1 = rotl32(x1, (r)); x1 ^= x0; }
  TF_RND(13) TF_RND(15) TF_RND(26) TF_RND(6)
  x0 += k1;  x1 += ks2 + 1u;
  TF_RND(17) TF_RND(29) TF_RND(16) TF_RND(24)
  x0 += ks2; x1 += k0 + 2u;
  TF_RND(13) TF_RND(15) TF_RND(26) TF_RND(6)
  x0 += k0;  x1 += k1 + 3u;
  TF_RND(17) TF_RND(29) TF_RND(16) TF_RND(24)
  x0 += k1;  x1 += ks2 + 4u;
  TF_RND(13) TF_RND(15) TF_RND(26) TF_RND(6)
  x0 += ks2; x1 += k0 + 5u;
#undef TF_RND
  o0 = x0; o1 = x1;
}

__device__ __forceinline__ void step_key(int i, unsigned& k0, unsigned& k1) {
  tf2x32(0u, 42u, 0u, (unsigned)i, k0, k1);
}
__device__ __forceinline__ unsigned elem_bits(unsigned k0, unsigned k1, unsigned m) {
  unsigned o0, o1;
  tf2x32(k0, k1, 0u, m, o0, o1);
  return o0 ^ o1;
}

// -------- XLA f32 tanh (EmitFastTanh, with_fma=true -> fmuladd Horner) -------
__device__ __forceinline__ float xla_tanh_f32(float x) {
  const float kMax = 7.90531110763549805f;
  float xc = fminf(fmaxf(x, -kMax), kMax);
  float x2 = xc * xc;
  float p = -2.76076847742355e-16f;
  p = __builtin_fmaf(x2, p, 2.00018790482477e-13f);
  p = __builtin_fmaf(x2, p, -8.60467152213735e-11f);
  p = __builtin_fmaf(x2, p, 5.12229709037114e-08f);
  p = __builtin_fmaf(x2, p, 1.48572235717979e-05f);
  p = __builtin_fmaf(x2, p, 6.37261928875436e-04f);
  p = __builtin_fmaf(x2, p, 4.89352455891786e-03f);
  float num = xc * p;
  float q = 1.19825839466702e-06f;
  q = __builtin_fmaf(x2, q, 1.18534705686654e-04f);
  q = __builtin_fmaf(x2, q, 2.26843463243900e-03f);
  q = __builtin_fmaf(x2, q, 4.89352518554385e-03f);
  float r = num / q;
  return (fabsf(x) < 0.0004f) ? x : r;
}

// ---------------- XLA f32 log (Cephes, plain fmul/fadd as in VF32Log) --------
__device__ __forceinline__ float xla_log_f32(float x) {
#pragma clang fp contract(off)
  unsigned bits = __float_as_uint(x);
  int e = (int)((bits >> 23) & 0xffu) - 126;          // x = m * 2^e, m in [0.5,1)
  float m = __uint_as_float((bits & 0x007fffffu) | 0x3f000000u);
  bool c = m < 0.707106781186547524f;                 // sqrt(0.5)
  e = c ? (e - 1) : e;
  m = c ? (m + m) : m;
  m = m - 1.0f;
  float z = m * m;
  float y = 7.0376836292e-2f;
  y = y * m + (-1.1514610310e-1f);
  y = y * m + 1.1676998740e-1f;
  y = y * m + (-1.2420140846e-1f);
  y = y * m + 1.4249322787e-1f;
  y = y * m + (-1.6668057665e-1f);
  y = y * m + 2.0000714765e-1f;
  y = y * m + (-2.4999993993e-1f);
  y = y * m + 3.3333331174e-1f;
  y = y * m;
  y = y * z;
  float ef = (float)e;
  float t1 = ef * (-2.12194440e-4f);
  y = y + t1;
  float t2 = z * 0.5f;
  y = y - t2;
  float r = m + y;
  float t3 = ef * 0.693359375f;
  r = r + t3;
  return r;
}

// ---------------- setup kernels (f32, gold-faithful orders) ----------------

__global__ void k_hbar(const float* __restrict__ H, float* __restrict__ Hbar) {
#pragma clang fp contract(off)
  int idx = blockIdx.x * 256 + threadIdx.x;  // 1024*512
  int b = idx >> 9, d = idx & 511;
  const float* p = H + (size_t)b * NNODE * DH + d;
  float s = 0.0f;
  for (int n = 0; n < NNODE; n++) s = s + p[(size_t)n * DH];
  Hbar[idx] = s / 200.0f;
}

// KT[b][k][n] = FMA-chain over d ascending of H[b,n,d]*WK[d,k]  (transposed layout)
__global__ __launch_bounds__(256) void k_K(const float* __restrict__ H,
                                           const float* __restrict__ WK,
                                           float* __restrict__ KT) {
  __shared__ float hr[8][DH];        // 16 KiB
  __shared__ float ts[DK * 9];       // retile pad-9, conflict-free
  int g = blockIdx.x;                // 1024*25 blocks, 8 rows each
  int b = g / 25;
  int r0 = (g % 25) * 8;
  int t = threadIdx.x;
  const float* Hb = H + (size_t)b * NNODE * DH + (size_t)r0 * DH;
  for (int e = t; e < 8 * DH; e += 256) hr[e >> 9][e & 511] = Hb[e];
  __syncthreads();
  int k0 = t, k1 = t + 256;
  float a[8][2];
#pragma unroll
  for (int r = 0; r < 8; r++) { a[r][0] = 0.0f; a[r][1] = 0.0f; }
  for (int d = 0; d < DH; d++) {
    float w0 = WK[(size_t)d * DK + k0], w1 = WK[(size_t)d * DK + k1];
#pragma unroll
    for (int r = 0; r < 8; r++) {
      a[r][0] = __builtin_fmaf(hr[r][d], w0, a[r][0]);
      a[r][1] = __builtin_fmaf(hr[r][d], w1, a[r][1]);
    }
  }
#pragma unroll
  for (int r = 0; r < 8; r++) {
    ts[k0 * 9 + r] = a[r][0];
    ts[k1 * 9 + r] = a[r][1];
  }
  __syncthreads();
  float* Ko = KT + (size_t)b * DK * NNODE + r0;
  for (int i = t; i < DK * 8; i += 256) {
    int k = i >> 3, r = i & 7;
    Ko[(size_t)k * NNODE + r] = ts[k * 9 + r];
  }
}

// acc[b][j] = FMA-chain k=0..511 of Hbar[b,k]*WQ[k,j] (prefix of the 1536-chain)
__global__ __launch_bounds__(256) void k_acc512(const float* __restrict__ Hbar,
                                                const float* __restrict__ WQ,
                                                float* __restrict__ acc) {
  __shared__ float hb[DH];
  int b = blockIdx.x, t = threadIdx.x;
  for (int e = t; e < DH; e += 256) hb[e] = Hbar[(size_t)b * DH + e];
  __syncthreads();
  int j0 = t, j1 = t + 256;
  float a0 = 0.0f, a1 = 0.0f;
  for (int k = 0; k < DH; k++) {
    float w0 = WQ[(size_t)k * DK + j0], w1 = WQ[(size_t)k * DK + j1];
    a0 = __builtin_fmaf(hb[k], w0, a0);
    a1 = __builtin_fmaf(hb[k], w1, a1);
  }
  acc[(size_t)b * DK + j0] = a0;
  acc[(size_t)b * DK + j1] = a1;
}

// ---------------- the fused 200-step decoder: one block owns G batch rows ----
// 1024 threads: Q-phase on t<512 (4 chains/thread, shared W loads);
// U-phase one-pass: quarter q = t>>8 owns bb=q with 256 lanes.
__global__ __launch_bounds__(TPB) void k_mega(const float* __restrict__ KT,
                                              const float* __restrict__ acc,
                                              const float* __restrict__ WQ,
                                              const float* __restrict__ H,
                                              const float* __restrict__ v1,
                                              const float* __restrict__ vf,
                                              int* __restrict__ out) {
  __shared__ float hpI[DH][G];     // interleaved [k][bb] : current pick
  __shared__ float hp0I[DH][G];    // first pick (frozen after step 0)
  __shared__ float Qs[G][DK];
  __shared__ float accs[G][DK];
  __shared__ float zl[G][NNODE];
  __shared__ int   pil[G];
  int t = threadIdx.x;
  int b0 = blockIdx.x * G;

  for (int e = t; e < G * DK; e += TPB) {
    int bb = e >> 9, j = e & 511;
    accs[bb][j] = acc[(size_t)(b0 + bb) * DK + j];
  }
  for (int e = t; e < DH; e += TPB) {
    float a = v1[e], bv = vf[e];
#pragma unroll
    for (int bb = 0; bb < G; bb++) { hpI[e][bb] = a; hp0I[e][bb] = bv; }
  }
  __syncthreads();

  for (int step = 0; step < NSTEP; step++) {
    // ---- Q phase (threads 0..511): thread owns column j=t; 4 chains.
    if (t < 512) {
      float a0 = accs[0][t], a1 = accs[1][t], a2 = accs[2][t], a3 = accs[3][t];
      const float* Wp = WQ + (size_t)512 * DK + t;
      for (int k = 0; k < DH; k += 4) {
        float w0 = Wp[(size_t)(k + 0) * DK];
        float w1 = Wp[(size_t)(k + 1) * DK];
        float w2 = Wp[(size_t)(k + 2) * DK];
        float w3 = Wp[(size_t)(k + 3) * DK];
        float4 h0 = *(const float4*)&hpI[k + 0][0];
        float4 h1 = *(const float4*)&hpI[k + 1][0];
        float4 h2 = *(const float4*)&hpI[k + 2][0];
        float4 h3 = *(const float4*)&hpI[k + 3][0];
        a0 = __builtin_fmaf(h0.x, w0, a0); a1 = __builtin_fmaf(h0.y, w0, a1);
        a2 = __builtin_fmaf(h0.z, w0, a2); a3 = __builtin_fmaf(h0.w, w0, a3);
        a0 = __builtin_fmaf(h1.x, w1, a0); a1 = __builtin_fmaf(h1.y, w1, a1);
        a2 = __builtin_fmaf(h1.z, w1, a2); a3 = __builtin_fmaf(h1.w, w1, a3);
        a0 = __builtin_fmaf(h2.x, w2, a0); a1 = __builtin_fmaf(h2.y, w2, a1);
        a2 = __builtin_fmaf(h2.z, w2, a2); a3 = __builtin_fmaf(h2.w, w2, a3);
        a0 = __builtin_fmaf(h3.x, w3, a0); a1 = __builtin_fmaf(h3.y, w3, a1);
        a2 = __builtin_fmaf(h3.z, w3, a2); a3 = __builtin_fmaf(h3.w, w3, a3);
      }
      const float* Wp2 = WQ + (size_t)1024 * DK + t;
      for (int k = 0; k < DH; k += 4) {
        float w0 = Wp2[(size_t)(k + 0) * DK];
        float w1 = Wp2[(size_t)(k + 1) * DK];
        float w2 = Wp2[(size_t)(k + 2) * DK];
        float w3 = Wp2[(size_t)(k + 3) * DK];
        float4 h0 = *(const float4*)&hp0I[k + 0][0];
        float4 h1 = *(const float4*)&hp0I[k + 1][0];
        float4 h2 = *(const float4*)&hp0I[k + 2][0];
        float4 h3 = *(const float4*)&hp0I[k + 3][0];
        a0 = __builtin_fmaf(h0.x, w0, a0); a1 = __builtin_fmaf(h0.y, w0, a1);
        a2 = __builtin_fmaf(h0.z, w0, a2); a3 = __builtin_fmaf(h0.w, w0, a3);
        a0 = __builtin_fmaf(h1.x, w1, a0); a1 = __builtin_fmaf(h1.y, w1, a1);
        a2 = __builtin_fmaf(h1.z, w1, a2); a3 = __builtin_fmaf(h1.w, w1, a3);
        a0 = __builtin_fmaf(h2.x, w2, a0); a1 = __builtin_fmaf(h2.y, w2, a1);
        a2 = __builtin_fmaf(h2.z, w2, a2); a3 = __builtin_fmaf(h2.w, w2, a3);
        a0 = __builtin_fmaf(h3.x, w3, a0); a1 = __builtin_fmaf(h3.y, w3, a1);
        a2 = __builtin_fmaf(h3.z, w3, a2); a3 = __builtin_fmaf(h3.w, w3, a3);
      }
      Qs[0][t] = a0; Qs[1][t] = a1; Qs[2][t] = a2; Qs[3][t] = a3;
    }
    __syncthreads();

    // ---- U/z phase: quarter q=t>>8 owns bb=q, lane tl=t&255; one pass.
    int bb = t >> 8;
    int tl = t & 255;
    int b = b0 + bb;
    if (tl < NNODE) {
#pragma clang fp contract(off)
      const float* Kb = KT + (size_t)b * DK * NNODE;
      float l[16];
#pragma unroll
      for (int j = 0; j < 16; j++) l[j] = 0.0f;
      float kb[16];
#pragma unroll
      for (int u = 0; u < 16; u++)          // prefetch chunk 0
        kb[u] = Kb[(size_t)u * NNODE + tl];
      for (int c = 0; c < DK / 16; c++) {   // 32 chunks, k ascending
        float kn[16];
        if (c < DK / 16 - 1) {
#pragma unroll
          for (int u = 0; u < 16; u++)      // prefetch chunk c+1 (indep loads)
            kn[u] = Kb[(size_t)((c + 1) * 16 + u) * NNODE + tl];
        }
#pragma unroll
        for (int u = 0; u < 16; u++) {
          float prod = kb[u] * Qs[bb][c * 16 + u];  // separate mul rounding
          l[u] = l[u] + prod;                       // lane-strided fadd
        }
#pragma unroll
        for (int u = 0; u < 16; u++) kb[u] = kn[u];
      }
      // shuffle-halving horizontal reduce over 16 lanes:
#pragma unroll
      for (int j = 0; j < 8; j++) l[j] = l[j] + l[j + 8];
#pragma unroll
      for (int j = 0; j < 4; j++) l[j] = l[j] + l[j + 4];
#pragma unroll
      for (int j = 0; j < 2; j++) l[j] = l[j] + l[j + 2];
      float U = l[0] + l[1];
      const float inv = 1.0f / sqrtf(512.0f);
      float u = U * inv;
      float logit = 10.0f * xla_tanh_f32(u);
      unsigned kk0, kk1;
      step_key(step, kk0, kk1);
      unsigned bits = elem_bits(kk0, kk1, (unsigned)(b * NNODE + tl));
      unsigned fb = (bits >> 9) | 0x3F800000u;
      float uf = __uint_as_float(fb) - 1.0f;    // [0,1), exact
      const float tinyf = 1.17549435e-38f;
      float v = uf * 1.0f;
      v = v + tinyf;
      v = fmaxf(tinyf, v);
      float L1 = xla_log_f32(v);
      float gmb = -xla_log_f32(-L1);
      zl[bb][tl] = gmb + logit;
    }
    __syncthreads();
    if (tl < 64) {  // wave0 of each quarter: argmax, first-occurrence tie rule
      float bv = -__builtin_inff();
      int bi = 0;
      for (int n = tl; n < NNODE; n += 64) {
        float zv = zl[bb][n];
        if (zv > bv) { bv = zv; bi = n; }
      }
      for (int off = 32; off; off >>= 1) {
        float ov = __shfl_down(bv, off);
        int   oi = __shfl_down(bi, off);
        if (ov > bv || (ov == bv && oi < bi)) { bv = ov; bi = oi; }
      }
      if (tl == 0) {
        pil[bb] = bi;
        out[b * (NSTEP + 1) + step + 1] = bi;
        if (step == 0) out[b * (NSTEP + 1)] = bi;  // duplicated step-0 pick
      }
    }
    __syncthreads();
    {   // gather H[b, pi] into hpI (exact copy)
      int pi = pil[bb];
      const float* src = H + ((size_t)b * NNODE + pi) * DH;
      for (int e = tl; e < DH; e += 256) hpI[e][bb] = src[e];
    }
    __syncthreads();
    if (step == 0) {  // freeze H_pi_1 = step-0 pick
      for (int e = t; e < DH * G; e += TPB) hp0I[e >> 2][e & 3] = hpI[e >> 2][e & 3];
      __syncthreads();
    }
  }
}

extern "C" void kernel_launch(void* const* d_in, const int* in_sizes, int n_in,
                              void* d_out, int out_size, void* d_ws, size_t ws_size,
                              hipStream_t stream) {
  (void)in_sizes; (void)n_in; (void)out_size; (void)ws_size;
  const float* H  = (const float*)d_in[1];
  const float* WQ = (const float*)d_in[2];
  const float* WK = (const float*)d_in[3];
  const float* v1 = (const float*)d_in[4];
  const float* vf = (const float*)d_in[5];
  int* out = (int*)d_out;

  float* ws = (float*)d_ws;
  const size_t KSZ = (size_t)BSZ * NNODE * DK;  // 419.4 MB
  const size_t S = (size_t)BSZ * 512;
  float* KT   = ws;
  float* Hbar = ws + KSZ;
  float* acc  = ws + KSZ + S;

  k_hbar  <<<2048, 256, 0, stream>>>(H, Hbar);
  k_K     <<<BSZ * 25, 256, 0, stream>>>(H, WK, KT);
  k_acc512<<<BSZ, 256, 0, stream>>>(Hbar, WQ, acc);
  k_mega  <<<BSZ / G, TPB, 0, stream>>>(KT, acc, WQ, H, v1, vf, out);
}